// Round 7
// baseline (288.757 us; speedup 1.0000x reference)
//
#include <hip/hip_runtime.h>
#include <hip/hip_bf16.h>

typedef unsigned short u16;
typedef unsigned int u32;
typedef __bf16 bf16x8 __attribute__((ext_vector_type(8)));
typedef float f32x4 __attribute__((ext_vector_type(4)));

#define NN 50000
#define NE 640000
#define DH 128
#define NTILES (NN / 16)        // 3125, exact
#define NBLK ((NN + 255) / 256) // 196 scan blocks

__device__ __forceinline__ u16 f2bf(float f) {
  u32 i = __float_as_uint(f);
  u32 r = (i + 0x7FFFu + ((i >> 16) & 1u)) >> 16;   // RNE
  return (u16)r;
}
__device__ __forceinline__ float bflo(u32 v) { return __uint_as_float(v << 16); }
__device__ __forceinline__ float bfhi(u32 v) { return __uint_as_float(v & 0xFFFF0000u); }

// ------- cast x + all weights fp32 -> bf16, and zero cnt (one launch) --------
// wb layout (elements): pre_w@0, wl0@16384, wr0@32768, wl1@49152, wr1@65536, lin_w@81920
__global__ void cast_all(const float* __restrict__ x,
                         const float* __restrict__ pw, const float* __restrict__ wl0,
                         const float* __restrict__ wr0, const float* __restrict__ wl1,
                         const float* __restrict__ wr1, const float* __restrict__ lw,
                         u16* __restrict__ xb, u16* __restrict__ wb,
                         int* __restrict__ cnt) {
  int idx = blockIdx.x * blockDim.x + threadIdx.x;
  long i4 = (long)idx * 4;
  const long XCNT = (long)NN * DH;      // 6,400,000
  const long WCNT = 114688;
  if (i4 < XCNT) {
    float4 v = *(const float4*)(x + i4);
    u32 a = (u32)f2bf(v.x) | ((u32)f2bf(v.y) << 16);
    u32 b = (u32)f2bf(v.z) | ((u32)f2bf(v.w) << 16);
    *(uint2*)(xb + i4) = make_uint2(a, b);
  } else if (i4 < XCNT + WCNT) {
    long w = i4 - XCNT;
    const float* src; long off;
    if (w < 16384)      { src = pw;  off = 0; }
    else if (w < 32768) { src = wl0; off = 16384; }
    else if (w < 49152) { src = wr0; off = 32768; }
    else if (w < 65536) { src = wl1; off = 49152; }
    else if (w < 81920) { src = wr1; off = 65536; }
    else                { src = lw;  off = 81920; }
    float4 v = *(const float4*)(src + (w - off));
    u32 a = (u32)f2bf(v.x) | ((u32)f2bf(v.y) << 16);
    u32 b = (u32)f2bf(v.z) | ((u32)f2bf(v.w) << 16);
    *(uint2*)(wb + w) = make_uint2(a, b);
  } else if (i4 < XCNT + WCNT + NN) {
    long c = i4 - XCNT - WCNT;           // NN divisible by 4
    *(int4*)(cnt + c) = make_int4(0, 0, 0, 0);
  }
}

// ---------------- CSR build ----------------
__global__ void count_kernel(const int* __restrict__ ei, int* __restrict__ cnt) {
  int e = blockIdx.x * blockDim.x + threadIdx.x;
  if (e < NE) atomicAdd(&cnt[ei[NE + e]], 1);
}

__global__ __launch_bounds__(256) void scan_part(const int* __restrict__ cnt,
                                                 int* __restrict__ partial) {
  __shared__ int sm[4];
  int i = blockIdx.x * 256 + threadIdx.x;
  int s = (i < NN) ? cnt[i] : 0;
  s += __shfl_xor(s, 1);  s += __shfl_xor(s, 2);  s += __shfl_xor(s, 4);
  s += __shfl_xor(s, 8);  s += __shfl_xor(s, 16); s += __shfl_xor(s, 32);
  if ((threadIdx.x & 63) == 0) sm[threadIdx.x >> 6] = s;
  __syncthreads();
  if (threadIdx.x == 0) partial[blockIdx.x] = sm[0] + sm[1] + sm[2] + sm[3];
}

__global__ __launch_bounds__(256) void scan_top(int* __restrict__ partial) {
  __shared__ int sm[256];
  int tid = threadIdx.x;
  int v = (tid < NBLK) ? partial[tid] : 0;
  sm[tid] = v;
  __syncthreads();
  for (int d = 1; d < 256; d <<= 1) {
    int t = (tid >= d) ? sm[tid - d] : 0;
    __syncthreads();
    sm[tid] += t;
    __syncthreads();
  }
  if (tid < NBLK) partial[tid] = sm[tid] - v;   // exclusive prefix
}

__global__ __launch_bounds__(256) void scan_final(const int* __restrict__ cnt,
                                                  const int* __restrict__ partial,
                                                  int* __restrict__ off,
                                                  int* __restrict__ fillpos) {
  __shared__ int sm[256];
  int tid = threadIdx.x;
  int i = blockIdx.x * 256 + tid;
  int v = (i < NN) ? cnt[i] : 0;
  sm[tid] = v;
  __syncthreads();
  for (int d = 1; d < 256; d <<= 1) {
    int t = (tid >= d) ? sm[tid - d] : 0;
    __syncthreads();
    sm[tid] += t;
    __syncthreads();
  }
  int excl = sm[tid] - v + partial[blockIdx.x];
  if (i < NN) { off[i] = excl; fillpos[i] = excl; }
  if (i == 0) off[NN] = NE;
}

__global__ void fill_kernel(const int* __restrict__ ei, int* __restrict__ fillpos,
                            int* __restrict__ srcs) {
  int e = blockIdx.x * blockDim.x + threadIdx.x;
  if (e < NE) {
    int d = ei[NE + e];
    int p = atomicAdd(&fillpos[d], 1);
    srcs[p] = ei[e];
  }
}

// ---------------- mean aggregation: agg[i] = mean_{e: dst=i} h[src[e]] --------
__global__ __launch_bounds__(256) void agg_kernel(const u16* __restrict__ h,
                                                  const int* __restrict__ off,
                                                  const int* __restrict__ srcs,
                                                  u16* __restrict__ agg) {
  int node = blockIdx.x * 4 + (threadIdx.x >> 6);
  int lane = threadIdx.x & 63;
  int sub = lane >> 4;        // 0..3: which edge of the quad
  int c16 = lane & 15;        // which 16B chunk of the row
  int e0 = off[node], e1 = off[node + 1];
  float a0=0,a1=0,a2=0,a3=0,a4=0,a5=0,a6=0,a7=0;
  for (int e = e0 + sub; e < e1; e += 4) {
    int s = srcs[e];
    uint4 v = *(const uint4*)(h + (size_t)s * DH + c16 * 8);
    a0 += bflo(v.x); a1 += bfhi(v.x);
    a2 += bflo(v.y); a3 += bfhi(v.y);
    a4 += bflo(v.z); a5 += bfhi(v.z);
    a6 += bflo(v.w); a7 += bfhi(v.w);
  }
  a0 += __shfl_xor(a0,16); a0 += __shfl_xor(a0,32);
  a1 += __shfl_xor(a1,16); a1 += __shfl_xor(a1,32);
  a2 += __shfl_xor(a2,16); a2 += __shfl_xor(a2,32);
  a3 += __shfl_xor(a3,16); a3 += __shfl_xor(a3,32);
  a4 += __shfl_xor(a4,16); a4 += __shfl_xor(a4,32);
  a5 += __shfl_xor(a5,16); a5 += __shfl_xor(a5,32);
  a6 += __shfl_xor(a6,16); a6 += __shfl_xor(a6,32);
  a7 += __shfl_xor(a7,16); a7 += __shfl_xor(a7,32);
  int deg = e1 - e0;
  float inv = 1.0f / (float)(deg > 0 ? deg : 1);
  if (sub == 0) {
    uint4 o;
    o.x = (u32)f2bf(a0 * inv) | ((u32)f2bf(a1 * inv) << 16);
    o.y = (u32)f2bf(a2 * inv) | ((u32)f2bf(a3 * inv) << 16);
    o.z = (u32)f2bf(a4 * inv) | ((u32)f2bf(a5 * inv) << 16);
    o.w = (u32)f2bf(a6 * inv) | ((u32)f2bf(a7 * inv) << 16);
    *(uint4*)(agg + (size_t)node * DH + c16 * 8) = o;
  }
}

// ---------------- fused GEMM (+optional second input) + bias + LN + ReLU ------
// LDS-staged epilogue: per-wave transpose tile, then 256B-segment dwordx4 stores
__global__ __launch_bounds__(256) void gemm_ln_relu(const u16* __restrict__ A1,
                                                    const u16* __restrict__ W1,
                                                    const u16* __restrict__ A2,
                                                    const u16* __restrict__ W2,
                                                    const float* __restrict__ bias,
                                                    const float* __restrict__ g,
                                                    const float* __restrict__ be,
                                                    u16* __restrict__ outh) {
  __shared__ u16 st[4][16 * 136];   // 136 u16 row stride: 272B, 16B-aligned rows
  int lane = threadIdx.x & 63;
  int wid = threadIdx.x >> 6;
  int ntile = blockIdx.x * 4 + wid;
  if (ntile >= NTILES) return;
  u16* smw = st[wid];
  int rA = lane & 15;       // A row within tile
  int ksel = lane >> 4;     // k sub-block 0..3
  int nodeA = ntile * 16 + rA;

  f32x4 acc[8];
  #pragma unroll
  for (int j = 0; j < 8; ++j) acc[j] = (f32x4){0.f,0.f,0.f,0.f};

  for (int pass = 0; pass < 2; ++pass) {
    const u16* A = pass ? A2 : A1;
    const u16* W = pass ? W2 : W1;
    if (!A) break;
    const u16* arow = A + (size_t)nodeA * DH + ksel * 8;
    const u16* wrow = W + (size_t)rA * DH + ksel * 8;
    #pragma unroll
    for (int ks = 0; ks < 4; ++ks) {
      bf16x8 af = *(const bf16x8*)(arow + ks * 32);
      #pragma unroll
      for (int jt = 0; jt < 8; ++jt) {
        bf16x8 bf = *(const bf16x8*)(wrow + ks * 32 + jt * 16 * DH);
        acc[jt] = __builtin_amdgcn_mfma_f32_16x16x32_bf16(af, bf, acc[jt], 0, 0, 0);
      }
    }
  }

  // epilogue: D[row=(lane>>4)*4+r][col=lane&15]
  int jcol = lane & 15;
  int rbase = (lane >> 4) * 4;
  float gv[8], bev[8];
  #pragma unroll
  for (int jt = 0; jt < 8; ++jt) {
    int j = jt * 16 + jcol;
    float bi = bias[j];
    gv[jt] = g[j]; bev[jt] = be[j];
    #pragma unroll
    for (int r = 0; r < 4; ++r) acc[jt][r] += bi;
  }
  #pragma unroll
  for (int r = 0; r < 4; ++r) {
    float s = 0.f;
    #pragma unroll
    for (int jt = 0; jt < 8; ++jt) s += acc[jt][r];
    s += __shfl_xor(s, 1); s += __shfl_xor(s, 2);
    s += __shfl_xor(s, 4); s += __shfl_xor(s, 8);
    float mean = s * (1.0f / 128.0f);
    float q = 0.f;
    #pragma unroll
    for (int jt = 0; jt < 8; ++jt) { float d = acc[jt][r] - mean; q += d * d; }
    q += __shfl_xor(q, 1); q += __shfl_xor(q, 2);
    q += __shfl_xor(q, 4); q += __shfl_xor(q, 8);
    float rs = rsqrtf(q * (1.0f / 128.0f) + 1e-5f);
    #pragma unroll
    for (int jt = 0; jt < 8; ++jt) {
      float y = (acc[jt][r] - mean) * rs * gv[jt] + bev[jt];
      y = fmaxf(y, 0.f);
      smw[(rbase + r) * 136 + jt * 16 + jcol] = f2bf(y);
    }
  }
  // readback: 4 insts, each = 4 rows x 256B contiguous segments
  int tbase = ntile * 16;
  #pragma unroll
  for (int t = 0; t < 4; ++t) {
    int idx = t * 64 + lane;
    int row = idx >> 4;
    int c = idx & 15;
    uint4 v = *(const uint4*)&smw[row * 136 + c * 8];
    *(uint4*)(outh + (size_t)(tbase + row) * DH + c * 8) = v;
  }
}

// ---------------- final linear + x-copy: out[n] = [x[n], h@lin_w.T + lin_b] ---
// 4 waves/block, per-wave LDS halved via two column-half passes -> 16 waves/CU
__global__ __launch_bounds__(256) void final_kernel(const u16* __restrict__ A,
                                                    const u16* __restrict__ W,
                                                    const float* __restrict__ bias,
                                                    const float* __restrict__ x,
                                                    float* __restrict__ out) {
  __shared__ float sm[4][16 * 132];   // 132-float row stride; 8448 B per wave
  int lane = threadIdx.x & 63;
  int wid = threadIdx.x >> 6;
  int ntile = blockIdx.x * 4 + wid;
  if (ntile >= NTILES) return;
  float* smw = sm[wid];
  int rA = lane & 15;
  int ksel = lane >> 4;
  int nodeA = ntile * 16 + rA;

  f32x4 acc[16];
  #pragma unroll
  for (int j = 0; j < 16; ++j) acc[j] = (f32x4){0.f,0.f,0.f,0.f};

  const u16* arow = A + (size_t)nodeA * DH + ksel * 8;
  const u16* wrow = W + (size_t)rA * DH + ksel * 8;
  #pragma unroll
  for (int ks = 0; ks < 4; ++ks) {
    bf16x8 af = *(const bf16x8*)(arow + ks * 32);
    #pragma unroll
    for (int jt = 0; jt < 16; ++jt) {
      bf16x8 bf = *(const bf16x8*)(wrow + ks * 32 + jt * 16 * DH);
      acc[jt] = __builtin_amdgcn_mfma_f32_16x16x32_bf16(af, bf, acc[jt], 0, 0, 0);
    }
  }

  int jcol = lane & 15;
  int rbase = (lane >> 4) * 4;
  int base = ntile * 16;

  // x -> out[:,0:128]: 8 insts, each 2 rows x 512B segments (last reader of x)
  #pragma unroll
  for (int t = 0; t < 8; ++t) {
    int idx = t * 64 + lane;
    int rr = idx >> 5;
    int cc = idx & 31;
    f32x4 v = __builtin_nontemporal_load((const f32x4*)(x + (size_t)(base + rr) * DH + cc * 4));
    __builtin_nontemporal_store(v, (f32x4*)(out + (size_t)(base + rr) * 384 + cc * 4));
  }

  // linear part in two column-half passes (cols 128:256, 256:384)
  #pragma unroll
  for (int half = 0; half < 2; ++half) {
    #pragma unroll
    for (int jt2 = 0; jt2 < 8; ++jt2) {
      int jt = half * 8 + jt2;
      float bv = bias[jt * 16 + jcol];
      #pragma unroll
      for (int r = 0; r < 4; ++r)
        smw[(rbase + r) * 132 + jt2 * 16 + jcol] = acc[jt][r] + bv;
    }
    // per-wave ds_write -> ds_read: LDS pipe is in-order within a wave
    #pragma unroll
    for (int t = 0; t < 8; ++t) {
      int idx = t * 64 + lane;
      int row = idx >> 5;
      int c = idx & 31;
      f32x4 v = *(const f32x4*)&smw[row * 132 + c * 4];
      __builtin_nontemporal_store(v,
          (f32x4*)(out + (size_t)(base + row) * 384 + 128 + half * 128 + c * 4));
    }
  }
}

extern "C" void kernel_launch(void* const* d_in, const int* in_sizes, int n_in,
                              void* d_out, int out_size, void* d_ws, size_t ws_size,
                              hipStream_t stream) {
  const float* x      = (const float*)d_in[0];
  const int*   ei     = (const int*)d_in[1];
  const float* pre_w  = (const float*)d_in[2];
  const float* pre_b  = (const float*)d_in[3];
  const float* pre_g  = (const float*)d_in[4];
  const float* pre_be = (const float*)d_in[5];
  const float* wl0    = (const float*)d_in[6];
  const float* wr0    = (const float*)d_in[7];
  const float* b0     = (const float*)d_in[8];
  const float* g0     = (const float*)d_in[9];
  const float* be0    = (const float*)d_in[10];
  const float* wl1    = (const float*)d_in[11];
  const float* wr1    = (const float*)d_in[12];
  const float* b1     = (const float*)d_in[13];
  const float* g1     = (const float*)d_in[14];
  const float* be1    = (const float*)d_in[15];
  const float* lin_w  = (const float*)d_in[16];
  const float* lin_b  = (const float*)d_in[17];
  float* out = (float*)d_out;

  char* ws = (char*)d_ws;
  size_t o = 0;
  auto alloc = [&](size_t bytes) { void* p = ws + o; o += (bytes + 255) & ~255ULL; return p; };
  u16* xb   = (u16*)alloc((size_t)NN * DH * 2);
  u16* hA   = (u16*)alloc((size_t)NN * DH * 2);
  u16* hB   = (u16*)alloc((size_t)NN * DH * 2);
  u16* aggb = (u16*)alloc((size_t)NN * DH * 2);
  u16* wb   = (u16*)alloc((size_t)114688 * 2);
  int* cnt     = (int*)alloc((size_t)NN * 4);
  int* off     = (int*)alloc((size_t)(NN + 1) * 4);
  int* fillpos = (int*)alloc((size_t)NN * 4);
  int* srcs    = (int*)alloc((size_t)NE * 4);
  int* partial = (int*)alloc((size_t)NBLK * 4);

  {
    long total4 = ((long)NN * DH + 114688 + NN) / 4;
    int blocks = (int)((total4 + 255) / 256);
    cast_all<<<blocks, 256, 0, stream>>>(x, pre_w, wl0, wr0, wl1, wr1, lin_w, xb, wb, cnt);
  }
  count_kernel<<<NE / 256, 256, 0, stream>>>(ei, cnt);
  scan_part<<<NBLK, 256, 0, stream>>>(cnt, partial);
  scan_top<<<1, 256, 0, stream>>>(partial);
  scan_final<<<NBLK, 256, 0, stream>>>(cnt, partial, off, fillpos);
  fill_kernel<<<NE / 256, 256, 0, stream>>>(ei, fillpos, srcs);

  int gblocks = (NTILES + 3) / 4;   // 782
  // pre-MP layer
  gemm_ln_relu<<<gblocks, 256, 0, stream>>>(xb, wb + 0, nullptr, nullptr,
                                            pre_b, pre_g, pre_be, hA);
  // SAGE layer 0
  agg_kernel<<<NN / 4, 256, 0, stream>>>(hA, off, srcs, aggb);
  gemm_ln_relu<<<gblocks, 256, 0, stream>>>(aggb, wb + 16384, hA, wb + 32768,
                                            b0, g0, be0, hB);
  // SAGE layer 1
  agg_kernel<<<NN / 4, 256, 0, stream>>>(hB, off, srcs, aggb);
  gemm_ln_relu<<<gblocks, 256, 0, stream>>>(aggb, wb + 49152, hB, wb + 65536,
                                            b1, g1, be1, hA);
  // output (linear + x concat fused)
  final_kernel<<<gblocks, 256, 0, stream>>>(hA, wb + 81920, lin_b, x, out);
}

// Round 8
// 274.697 us; speedup vs baseline: 1.0512x; 1.0512x over previous
//
#include <hip/hip_runtime.h>
#include <hip/hip_bf16.h>

typedef unsigned short u16;
typedef unsigned int u32;
typedef __bf16 bf16x8 __attribute__((ext_vector_type(8)));
typedef float f32x4 __attribute__((ext_vector_type(4)));

#define NN 50000
#define NE 640000
#define DH 128
#define NTILES (NN / 16)        // 3125, exact
#define NBLK ((NN + 255) / 256) // 196 scan blocks

__device__ __forceinline__ u16 f2bf(float f) {
  u32 i = __float_as_uint(f);
  u32 r = (i + 0x7FFFu + ((i >> 16) & 1u)) >> 16;   // RNE
  return (u16)r;
}
__device__ __forceinline__ float bflo(u32 v) { return __uint_as_float(v << 16); }
__device__ __forceinline__ float bfhi(u32 v) { return __uint_as_float(v & 0xFFFF0000u); }

// ------- cast x + all weights fp32 -> bf16, and zero cnt (one launch) --------
// wb layout (elements): pre_w@0, wl0@16384, wr0@32768, wl1@49152, wr1@65536, lin_w@81920
__global__ void cast_all(const float* __restrict__ x,
                         const float* __restrict__ pw, const float* __restrict__ wl0,
                         const float* __restrict__ wr0, const float* __restrict__ wl1,
                         const float* __restrict__ wr1, const float* __restrict__ lw,
                         u16* __restrict__ xb, u16* __restrict__ wb,
                         int* __restrict__ cnt) {
  int idx = blockIdx.x * blockDim.x + threadIdx.x;
  long i4 = (long)idx * 4;
  const long XCNT = (long)NN * DH;      // 6,400,000
  const long WCNT = 114688;
  if (i4 < XCNT) {
    float4 v = *(const float4*)(x + i4);
    u32 a = (u32)f2bf(v.x) | ((u32)f2bf(v.y) << 16);
    u32 b = (u32)f2bf(v.z) | ((u32)f2bf(v.w) << 16);
    *(uint2*)(xb + i4) = make_uint2(a, b);
  } else if (i4 < XCNT + WCNT) {
    long w = i4 - XCNT;
    const float* src; long off;
    if (w < 16384)      { src = pw;  off = 0; }
    else if (w < 32768) { src = wl0; off = 16384; }
    else if (w < 49152) { src = wr0; off = 32768; }
    else if (w < 65536) { src = wl1; off = 49152; }
    else if (w < 81920) { src = wr1; off = 65536; }
    else                { src = lw;  off = 81920; }
    float4 v = *(const float4*)(src + (w - off));
    u32 a = (u32)f2bf(v.x) | ((u32)f2bf(v.y) << 16);
    u32 b = (u32)f2bf(v.z) | ((u32)f2bf(v.w) << 16);
    *(uint2*)(wb + w) = make_uint2(a, b);
  } else if (i4 < XCNT + WCNT + NN) {
    long c = i4 - XCNT - WCNT;           // NN divisible by 4
    *(int4*)(cnt + c) = make_int4(0, 0, 0, 0);
  }
}

// ---------------- CSR build ----------------
__global__ void count_kernel(const int* __restrict__ ei, int* __restrict__ cnt) {
  int e = blockIdx.x * blockDim.x + threadIdx.x;
  if (e < NE) atomicAdd(&cnt[ei[NE + e]], 1);
}

__global__ __launch_bounds__(256) void scan_part(const int* __restrict__ cnt,
                                                 int* __restrict__ partial) {
  __shared__ int sm[4];
  int i = blockIdx.x * 256 + threadIdx.x;
  int s = (i < NN) ? cnt[i] : 0;
  s += __shfl_xor(s, 1);  s += __shfl_xor(s, 2);  s += __shfl_xor(s, 4);
  s += __shfl_xor(s, 8);  s += __shfl_xor(s, 16); s += __shfl_xor(s, 32);
  if ((threadIdx.x & 63) == 0) sm[threadIdx.x >> 6] = s;
  __syncthreads();
  if (threadIdx.x == 0) partial[blockIdx.x] = sm[0] + sm[1] + sm[2] + sm[3];
}

__global__ __launch_bounds__(256) void scan_top(int* __restrict__ partial) {
  __shared__ int sm[256];
  int tid = threadIdx.x;
  int v = (tid < NBLK) ? partial[tid] : 0;
  sm[tid] = v;
  __syncthreads();
  for (int d = 1; d < 256; d <<= 1) {
    int t = (tid >= d) ? sm[tid - d] : 0;
    __syncthreads();
    sm[tid] += t;
    __syncthreads();
  }
  if (tid < NBLK) partial[tid] = sm[tid] - v;   // exclusive prefix
}

__global__ __launch_bounds__(256) void scan_final(const int* __restrict__ cnt,
                                                  const int* __restrict__ partial,
                                                  int* __restrict__ off,
                                                  int* __restrict__ fillpos) {
  __shared__ int sm[256];
  int tid = threadIdx.x;
  int i = blockIdx.x * 256 + tid;
  int v = (i < NN) ? cnt[i] : 0;
  sm[tid] = v;
  __syncthreads();
  for (int d = 1; d < 256; d <<= 1) {
    int t = (tid >= d) ? sm[tid - d] : 0;
    __syncthreads();
    sm[tid] += t;
    __syncthreads();
  }
  int excl = sm[tid] - v + partial[blockIdx.x];
  if (i < NN) { off[i] = excl; fillpos[i] = excl; }
  if (i == 0) off[NN] = NE;
}

__global__ void fill_kernel(const int* __restrict__ ei, int* __restrict__ fillpos,
                            int* __restrict__ srcs) {
  int e = blockIdx.x * blockDim.x + threadIdx.x;
  if (e < NE) {
    int d = ei[NE + e];
    int p = atomicAdd(&fillpos[d], 1);
    srcs[p] = ei[e];
  }
}

// ---------------- mean aggregation: agg[i] = mean_{e: dst=i} h[src[e]] --------
__global__ __launch_bounds__(256) void agg_kernel(const u16* __restrict__ h,
                                                  const int* __restrict__ off,
                                                  const int* __restrict__ srcs,
                                                  u16* __restrict__ agg) {
  int node = blockIdx.x * 4 + (threadIdx.x >> 6);
  int lane = threadIdx.x & 63;
  int sub = lane >> 4;        // 0..3: which edge of the quad
  int c16 = lane & 15;        // which 16B chunk of the row
  int e0 = off[node], e1 = off[node + 1];
  float a0=0,a1=0,a2=0,a3=0,a4=0,a5=0,a6=0,a7=0;
  for (int e = e0 + sub; e < e1; e += 4) {
    int s = srcs[e];
    uint4 v = *(const uint4*)(h + (size_t)s * DH + c16 * 8);
    a0 += bflo(v.x); a1 += bfhi(v.x);
    a2 += bflo(v.y); a3 += bfhi(v.y);
    a4 += bflo(v.z); a5 += bfhi(v.z);
    a6 += bflo(v.w); a7 += bfhi(v.w);
  }
  a0 += __shfl_xor(a0,16); a0 += __shfl_xor(a0,32);
  a1 += __shfl_xor(a1,16); a1 += __shfl_xor(a1,32);
  a2 += __shfl_xor(a2,16); a2 += __shfl_xor(a2,32);
  a3 += __shfl_xor(a3,16); a3 += __shfl_xor(a3,32);
  a4 += __shfl_xor(a4,16); a4 += __shfl_xor(a4,32);
  a5 += __shfl_xor(a5,16); a5 += __shfl_xor(a5,32);
  a6 += __shfl_xor(a6,16); a6 += __shfl_xor(a6,32);
  a7 += __shfl_xor(a7,16); a7 += __shfl_xor(a7,32);
  int deg = e1 - e0;
  float inv = 1.0f / (float)(deg > 0 ? deg : 1);
  if (sub == 0) {
    uint4 o;
    o.x = (u32)f2bf(a0 * inv) | ((u32)f2bf(a1 * inv) << 16);
    o.y = (u32)f2bf(a2 * inv) | ((u32)f2bf(a3 * inv) << 16);
    o.z = (u32)f2bf(a4 * inv) | ((u32)f2bf(a5 * inv) << 16);
    o.w = (u32)f2bf(a6 * inv) | ((u32)f2bf(a7 * inv) << 16);
    *(uint4*)(agg + (size_t)node * DH + c16 * 8) = o;
  }
}

// ---------------- fused GEMM (+optional second input) + bias + LN + ReLU ------
// LDS-staged epilogue: per-wave transpose tile, then 256B-segment dwordx4 stores
__global__ __launch_bounds__(256) void gemm_ln_relu(const u16* __restrict__ A1,
                                                    const u16* __restrict__ W1,
                                                    const u16* __restrict__ A2,
                                                    const u16* __restrict__ W2,
                                                    const float* __restrict__ bias,
                                                    const float* __restrict__ g,
                                                    const float* __restrict__ be,
                                                    u16* __restrict__ outh) {
  __shared__ u16 st[4][16 * 136];   // 136 u16 row stride: 272B, 16B-aligned rows
  int lane = threadIdx.x & 63;
  int wid = threadIdx.x >> 6;
  int ntile = blockIdx.x * 4 + wid;
  if (ntile >= NTILES) return;
  u16* smw = st[wid];
  int rA = lane & 15;       // A row within tile
  int ksel = lane >> 4;     // k sub-block 0..3
  int nodeA = ntile * 16 + rA;

  f32x4 acc[8];
  #pragma unroll
  for (int j = 0; j < 8; ++j) acc[j] = (f32x4){0.f,0.f,0.f,0.f};

  for (int pass = 0; pass < 2; ++pass) {
    const u16* A = pass ? A2 : A1;
    const u16* W = pass ? W2 : W1;
    if (!A) break;
    const u16* arow = A + (size_t)nodeA * DH + ksel * 8;
    const u16* wrow = W + (size_t)rA * DH + ksel * 8;
    #pragma unroll
    for (int ks = 0; ks < 4; ++ks) {
      bf16x8 af = *(const bf16x8*)(arow + ks * 32);
      #pragma unroll
      for (int jt = 0; jt < 8; ++jt) {
        bf16x8 bf = *(const bf16x8*)(wrow + ks * 32 + jt * 16 * DH);
        acc[jt] = __builtin_amdgcn_mfma_f32_16x16x32_bf16(af, bf, acc[jt], 0, 0, 0);
      }
    }
  }

  // epilogue: D[row=(lane>>4)*4+r][col=lane&15]
  int jcol = lane & 15;
  int rbase = (lane >> 4) * 4;
  float gv[8], bev[8];
  #pragma unroll
  for (int jt = 0; jt < 8; ++jt) {
    int j = jt * 16 + jcol;
    float bi = bias[j];
    gv[jt] = g[j]; bev[jt] = be[j];
    #pragma unroll
    for (int r = 0; r < 4; ++r) acc[jt][r] += bi;
  }
  #pragma unroll
  for (int r = 0; r < 4; ++r) {
    float s = 0.f;
    #pragma unroll
    for (int jt = 0; jt < 8; ++jt) s += acc[jt][r];
    s += __shfl_xor(s, 1); s += __shfl_xor(s, 2);
    s += __shfl_xor(s, 4); s += __shfl_xor(s, 8);
    float mean = s * (1.0f / 128.0f);
    float q = 0.f;
    #pragma unroll
    for (int jt = 0; jt < 8; ++jt) { float d = acc[jt][r] - mean; q += d * d; }
    q += __shfl_xor(q, 1); q += __shfl_xor(q, 2);
    q += __shfl_xor(q, 4); q += __shfl_xor(q, 8);
    float rs = rsqrtf(q * (1.0f / 128.0f) + 1e-5f);
    #pragma unroll
    for (int jt = 0; jt < 8; ++jt) {
      float y = (acc[jt][r] - mean) * rs * gv[jt] + bev[jt];
      y = fmaxf(y, 0.f);
      smw[(rbase + r) * 136 + jt * 16 + jcol] = f2bf(y);
    }
  }
  // readback: 4 insts, each = 4 rows x 256B contiguous segments
  int tbase = ntile * 16;
  #pragma unroll
  for (int t = 0; t < 4; ++t) {
    int idx = t * 64 + lane;
    int row = idx >> 4;
    int c = idx & 15;
    uint4 v = *(const uint4*)&smw[row * 136 + c * 8];
    *(uint4*)(outh + (size_t)(tbase + row) * DH + c * 8) = v;
  }
}

// ---------------- final linear + x-copy: out[n] = [x[n], h@lin_w.T + lin_b] ---
// 1 wave per block (grid = NTILES exact), VGPR cap 128 for deep W-load
// pipelining, regular cached stores (L2 write-combining)
__global__ __launch_bounds__(64, 4) void final_kernel(const u16* __restrict__ A,
                                                      const u16* __restrict__ W,
                                                      const float* __restrict__ bias,
                                                      const float* __restrict__ x,
                                                      float* __restrict__ out) {
  __shared__ float smw[16 * 132];   // 8448 B per block
  int lane = threadIdx.x;
  int ntile = blockIdx.x;
  int rA = lane & 15;
  int ksel = lane >> 4;
  int nodeA = ntile * 16 + rA;

  f32x4 acc[16];
  #pragma unroll
  for (int j = 0; j < 16; ++j) acc[j] = (f32x4){0.f,0.f,0.f,0.f};

  const u16* arow = A + (size_t)nodeA * DH + ksel * 8;
  const u16* wrow = W + (size_t)rA * DH + ksel * 8;
  #pragma unroll
  for (int ks = 0; ks < 4; ++ks) {
    bf16x8 af = *(const bf16x8*)(arow + ks * 32);
    #pragma unroll
    for (int jt = 0; jt < 16; ++jt) {
      bf16x8 bf = *(const bf16x8*)(wrow + ks * 32 + jt * 16 * DH);
      acc[jt] = __builtin_amdgcn_mfma_f32_16x16x32_bf16(af, bf, acc[jt], 0, 0, 0);
    }
  }

  int jcol = lane & 15;
  int rbase = (lane >> 4) * 4;
  int base = ntile * 16;

  // x -> out[:,0:128]: 8 insts, each 2 rows x 512B segments
  #pragma unroll
  for (int t = 0; t < 8; ++t) {
    int idx = t * 64 + lane;
    int rr = idx >> 5;
    int cc = idx & 31;
    f32x4 v = *(const f32x4*)(x + (size_t)(base + rr) * DH + cc * 4);
    *(f32x4*)(out + (size_t)(base + rr) * 384 + cc * 4) = v;
  }

  // linear part in two column-half passes (cols 128:256, 256:384)
  #pragma unroll
  for (int half = 0; half < 2; ++half) {
    #pragma unroll
    for (int jt2 = 0; jt2 < 8; ++jt2) {
      int jt = half * 8 + jt2;
      float bv = bias[jt * 16 + jcol];
      #pragma unroll
      for (int r = 0; r < 4; ++r)
        smw[(rbase + r) * 132 + jt2 * 16 + jcol] = acc[jt][r] + bv;
    }
    // per-wave ds_write -> ds_read: LDS pipe is in-order within a wave
    #pragma unroll
    for (int t = 0; t < 8; ++t) {
      int idx = t * 64 + lane;
      int row = idx >> 5;
      int c = idx & 31;
      f32x4 v = *(const f32x4*)&smw[row * 132 + c * 4];
      *(f32x4*)(out + (size_t)(base + row) * 384 + 128 + half * 128 + c * 4) = v;
    }
  }
}

extern "C" void kernel_launch(void* const* d_in, const int* in_sizes, int n_in,
                              void* d_out, int out_size, void* d_ws, size_t ws_size,
                              hipStream_t stream) {
  const float* x      = (const float*)d_in[0];
  const int*   ei     = (const int*)d_in[1];
  const float* pre_w  = (const float*)d_in[2];
  const float* pre_b  = (const float*)d_in[3];
  const float* pre_g  = (const float*)d_in[4];
  const float* pre_be = (const float*)d_in[5];
  const float* wl0    = (const float*)d_in[6];
  const float* wr0    = (const float*)d_in[7];
  const float* b0     = (const float*)d_in[8];
  const float* g0     = (const float*)d_in[9];
  const float* be0    = (const float*)d_in[10];
  const float* wl1    = (const float*)d_in[11];
  const float* wr1    = (const float*)d_in[12];
  const float* b1     = (const float*)d_in[13];
  const float* g1     = (const float*)d_in[14];
  const float* be1    = (const float*)d_in[15];
  const float* lin_w  = (const float*)d_in[16];
  const float* lin_b  = (const float*)d_in[17];
  float* out = (float*)d_out;

  char* ws = (char*)d_ws;
  size_t o = 0;
  auto alloc = [&](size_t bytes) { void* p = ws + o; o += (bytes + 255) & ~255ULL; return p; };
  u16* xb   = (u16*)alloc((size_t)NN * DH * 2);
  u16* hA   = (u16*)alloc((size_t)NN * DH * 2);
  u16* hB   = (u16*)alloc((size_t)NN * DH * 2);
  u16* aggb = (u16*)alloc((size_t)NN * DH * 2);
  u16* wb   = (u16*)alloc((size_t)114688 * 2);
  int* cnt     = (int*)alloc((size_t)NN * 4);
  int* off     = (int*)alloc((size_t)(NN + 1) * 4);
  int* fillpos = (int*)alloc((size_t)NN * 4);
  int* srcs    = (int*)alloc((size_t)NE * 4);
  int* partial = (int*)alloc((size_t)NBLK * 4);

  {
    long total4 = ((long)NN * DH + 114688 + NN) / 4;
    int blocks = (int)((total4 + 255) / 256);
    cast_all<<<blocks, 256, 0, stream>>>(x, pre_w, wl0, wr0, wl1, wr1, lin_w, xb, wb, cnt);
  }
  count_kernel<<<NE / 256, 256, 0, stream>>>(ei, cnt);
  scan_part<<<NBLK, 256, 0, stream>>>(cnt, partial);
  scan_top<<<1, 256, 0, stream>>>(partial);
  scan_final<<<NBLK, 256, 0, stream>>>(cnt, partial, off, fillpos);
  fill_kernel<<<NE / 256, 256, 0, stream>>>(ei, fillpos, srcs);

  int gblocks = (NTILES + 3) / 4;   // 782
  // pre-MP layer
  gemm_ln_relu<<<gblocks, 256, 0, stream>>>(xb, wb + 0, nullptr, nullptr,
                                            pre_b, pre_g, pre_be, hA);
  // SAGE layer 0
  agg_kernel<<<NN / 4, 256, 0, stream>>>(hA, off, srcs, aggb);
  gemm_ln_relu<<<gblocks, 256, 0, stream>>>(aggb, wb + 16384, hA, wb + 32768,
                                            b0, g0, be0, hB);
  // SAGE layer 1
  agg_kernel<<<NN / 4, 256, 0, stream>>>(hB, off, srcs, aggb);
  gemm_ln_relu<<<gblocks, 256, 0, stream>>>(aggb, wb + 49152, hB, wb + 65536,
                                            b1, g1, be1, hA);
  // output (linear + x concat fused)
  final_kernel<<<NTILES, 64, 0, stream>>>(hA, wb + 81920, lin_b, x, out);
}

// Round 9
// 274.479 us; speedup vs baseline: 1.0520x; 1.0008x over previous
//
#include <hip/hip_runtime.h>
#include <hip/hip_bf16.h>

typedef unsigned short u16;
typedef unsigned int u32;
typedef __bf16 bf16x8 __attribute__((ext_vector_type(8)));
typedef float f32x4 __attribute__((ext_vector_type(4)));

#define NN 50000
#define NE 640000
#define DH 128
#define NTILES (NN / 16)        // 3125, exact
#define NBLK ((NN + 255) / 256) // 196 scan blocks

__device__ __forceinline__ u16 f2bf(float f) {
  u32 i = __float_as_uint(f);
  u32 r = (i + 0x7FFFu + ((i >> 16) & 1u)) >> 16;   // RNE
  return (u16)r;
}
__device__ __forceinline__ float bflo(u32 v) { return __uint_as_float(v << 16); }
__device__ __forceinline__ float bfhi(u32 v) { return __uint_as_float(v & 0xFFFF0000u); }

// ------- cast x + all weights fp32 -> bf16, and zero cnt (one launch) --------
// wb layout (elements): pre_w@0, wl0@16384, wr0@32768, wl1@49152, wr1@65536, lin_w@81920
__global__ void cast_all(const float* __restrict__ x,
                         const float* __restrict__ pw, const float* __restrict__ wl0,
                         const float* __restrict__ wr0, const float* __restrict__ wl1,
                         const float* __restrict__ wr1, const float* __restrict__ lw,
                         u16* __restrict__ xb, u16* __restrict__ wb,
                         int* __restrict__ cnt) {
  int idx = blockIdx.x * blockDim.x + threadIdx.x;
  long i4 = (long)idx * 4;
  const long XCNT = (long)NN * DH;      // 6,400,000
  const long WCNT = 114688;
  if (i4 < XCNT) {
    float4 v = *(const float4*)(x + i4);
    u32 a = (u32)f2bf(v.x) | ((u32)f2bf(v.y) << 16);
    u32 b = (u32)f2bf(v.z) | ((u32)f2bf(v.w) << 16);
    *(uint2*)(xb + i4) = make_uint2(a, b);
  } else if (i4 < XCNT + WCNT) {
    long w = i4 - XCNT;
    const float* src; long off;
    if (w < 16384)      { src = pw;  off = 0; }
    else if (w < 32768) { src = wl0; off = 16384; }
    else if (w < 49152) { src = wr0; off = 32768; }
    else if (w < 65536) { src = wl1; off = 49152; }
    else if (w < 81920) { src = wr1; off = 65536; }
    else                { src = lw;  off = 81920; }
    float4 v = *(const float4*)(src + (w - off));
    u32 a = (u32)f2bf(v.x) | ((u32)f2bf(v.y) << 16);
    u32 b = (u32)f2bf(v.z) | ((u32)f2bf(v.w) << 16);
    *(uint2*)(wb + w) = make_uint2(a, b);
  } else if (i4 < XCNT + WCNT + NN) {
    long c = i4 - XCNT - WCNT;           // NN divisible by 4
    *(int4*)(cnt + c) = make_int4(0, 0, 0, 0);
  }
}

// ---------------- CSR build ----------------
__global__ void count_kernel(const int* __restrict__ ei, int* __restrict__ cnt) {
  int e = blockIdx.x * blockDim.x + threadIdx.x;
  if (e < NE) atomicAdd(&cnt[ei[NE + e]], 1);
}

__global__ __launch_bounds__(256) void scan_part(const int* __restrict__ cnt,
                                                 int* __restrict__ partial) {
  __shared__ int sm[4];
  int i = blockIdx.x * 256 + threadIdx.x;
  int s = (i < NN) ? cnt[i] : 0;
  s += __shfl_xor(s, 1);  s += __shfl_xor(s, 2);  s += __shfl_xor(s, 4);
  s += __shfl_xor(s, 8);  s += __shfl_xor(s, 16); s += __shfl_xor(s, 32);
  if ((threadIdx.x & 63) == 0) sm[threadIdx.x >> 6] = s;
  __syncthreads();
  if (threadIdx.x == 0) partial[blockIdx.x] = sm[0] + sm[1] + sm[2] + sm[3];
}

__global__ __launch_bounds__(256) void scan_top(int* __restrict__ partial) {
  __shared__ int sm[256];
  int tid = threadIdx.x;
  int v = (tid < NBLK) ? partial[tid] : 0;
  sm[tid] = v;
  __syncthreads();
  for (int d = 1; d < 256; d <<= 1) {
    int t = (tid >= d) ? sm[tid - d] : 0;
    __syncthreads();
    sm[tid] += t;
    __syncthreads();
  }
  if (tid < NBLK) partial[tid] = sm[tid] - v;   // exclusive prefix
}

__global__ __launch_bounds__(256) void scan_final(const int* __restrict__ cnt,
                                                  const int* __restrict__ partial,
                                                  int* __restrict__ off,
                                                  int* __restrict__ fillpos) {
  __shared__ int sm[256];
  int tid = threadIdx.x;
  int i = blockIdx.x * 256 + tid;
  int v = (i < NN) ? cnt[i] : 0;
  sm[tid] = v;
  __syncthreads();
  for (int d = 1; d < 256; d <<= 1) {
    int t = (tid >= d) ? sm[tid - d] : 0;
    __syncthreads();
    sm[tid] += t;
    __syncthreads();
  }
  int excl = sm[tid] - v + partial[blockIdx.x];
  if (i < NN) { off[i] = excl; fillpos[i] = excl; }
  if (i == 0) off[NN] = NE;
}

__global__ void fill_kernel(const int* __restrict__ ei, int* __restrict__ fillpos,
                            int* __restrict__ srcs) {
  int e = blockIdx.x * blockDim.x + threadIdx.x;
  if (e < NE) {
    int d = ei[NE + e];
    int p = atomicAdd(&fillpos[d], 1);
    srcs[p] = ei[e];
  }
}

// ---------------- mean aggregation: agg[i] = mean_{e: dst=i} h[src[e]] --------
__global__ __launch_bounds__(256) void agg_kernel(const u16* __restrict__ h,
                                                  const int* __restrict__ off,
                                                  const int* __restrict__ srcs,
                                                  u16* __restrict__ agg) {
  int node = blockIdx.x * 4 + (threadIdx.x >> 6);
  int lane = threadIdx.x & 63;
  int sub = lane >> 4;        // 0..3: which edge of the quad
  int c16 = lane & 15;        // which 16B chunk of the row
  int e0 = off[node], e1 = off[node + 1];
  float a0=0,a1=0,a2=0,a3=0,a4=0,a5=0,a6=0,a7=0;
  for (int e = e0 + sub; e < e1; e += 4) {
    int s = srcs[e];
    uint4 v = *(const uint4*)(h + (size_t)s * DH + c16 * 8);
    a0 += bflo(v.x); a1 += bfhi(v.x);
    a2 += bflo(v.y); a3 += bfhi(v.y);
    a4 += bflo(v.z); a5 += bfhi(v.z);
    a6 += bflo(v.w); a7 += bfhi(v.w);
  }
  a0 += __shfl_xor(a0,16); a0 += __shfl_xor(a0,32);
  a1 += __shfl_xor(a1,16); a1 += __shfl_xor(a1,32);
  a2 += __shfl_xor(a2,16); a2 += __shfl_xor(a2,32);
  a3 += __shfl_xor(a3,16); a3 += __shfl_xor(a3,32);
  a4 += __shfl_xor(a4,16); a4 += __shfl_xor(a4,32);
  a5 += __shfl_xor(a5,16); a5 += __shfl_xor(a5,32);
  a6 += __shfl_xor(a6,16); a6 += __shfl_xor(a6,32);
  a7 += __shfl_xor(a7,16); a7 += __shfl_xor(a7,32);
  int deg = e1 - e0;
  float inv = 1.0f / (float)(deg > 0 ? deg : 1);
  if (sub == 0) {
    uint4 o;
    o.x = (u32)f2bf(a0 * inv) | ((u32)f2bf(a1 * inv) << 16);
    o.y = (u32)f2bf(a2 * inv) | ((u32)f2bf(a3 * inv) << 16);
    o.z = (u32)f2bf(a4 * inv) | ((u32)f2bf(a5 * inv) << 16);
    o.w = (u32)f2bf(a6 * inv) | ((u32)f2bf(a7 * inv) << 16);
    *(uint4*)(agg + (size_t)node * DH + c16 * 8) = o;
  }
}

// ---------------- fused GEMM (+optional second input) + bias + LN + ReLU ------
// Column-quadrant: 1 block (4 waves) per 16-node tile; wave wid owns cols
// [wid*32, wid*32+32). Cross-wave LN via LDS partials (var = E[x^2]-mean^2).
__global__ __launch_bounds__(256) void gemm_ln_relu(const u16* __restrict__ A1,
                                                    const u16* __restrict__ W1,
                                                    const u16* __restrict__ A2,
                                                    const u16* __restrict__ W2,
                                                    const float* __restrict__ bias,
                                                    const float* __restrict__ g,
                                                    const float* __restrict__ be,
                                                    u16* __restrict__ outh) {
  __shared__ u16 st[16 * 136];        // block tile, 272B row stride (16B aligned)
  __shared__ float redS[4][16], redQ[4][16];
  int lane = threadIdx.x & 63;
  int wid = threadIdx.x >> 6;
  int ntile = blockIdx.x;             // grid == NTILES exactly
  int rA = lane & 15;
  int ksel = lane >> 4;
  int nodeA = ntile * 16 + rA;

  f32x4 acc[2];
  acc[0] = (f32x4){0.f,0.f,0.f,0.f};
  acc[1] = (f32x4){0.f,0.f,0.f,0.f};

  for (int pass = 0; pass < 2; ++pass) {
    const u16* A = pass ? A2 : A1;
    const u16* W = pass ? W2 : W1;
    if (!A) break;
    const u16* arow = A + (size_t)nodeA * DH + ksel * 8;
    #pragma unroll
    for (int ks = 0; ks < 4; ++ks) {
      bf16x8 af = *(const bf16x8*)(arow + ks * 32);
      #pragma unroll
      for (int jt = 0; jt < 2; ++jt) {
        // W row (output col) = wid*32 + jt*16 + rA
        const u16* wfrag = W + (size_t)(wid * 32 + jt * 16 + rA) * DH + ksel * 8 + ks * 32;
        bf16x8 bf = *(const bf16x8*)wfrag;
        acc[jt] = __builtin_amdgcn_mfma_f32_16x16x32_bf16(af, bf, acc[jt], 0, 0, 0);
      }
    }
  }

  // D[row=(lane>>4)*4+r][col(local 16)=lane&15]; global col = wid*32+jt*16+jcol
  int jcol = lane & 15;
  int rbase = (lane >> 4) * 4;
  float gv[2], bev[2];
  #pragma unroll
  for (int jt = 0; jt < 2; ++jt) {
    int j = wid * 32 + jt * 16 + jcol;
    float bi = bias[j];
    gv[jt] = g[j]; bev[jt] = be[j];
    #pragma unroll
    for (int r = 0; r < 4; ++r) acc[jt][r] += bi;
  }
  // per-wave partial sum / sumsq over this 32-col quadrant
  #pragma unroll
  for (int r = 0; r < 4; ++r) {
    float s = acc[0][r] + acc[1][r];
    float q = acc[0][r]*acc[0][r] + acc[1][r]*acc[1][r];
    s += __shfl_xor(s, 1); s += __shfl_xor(s, 2);
    s += __shfl_xor(s, 4); s += __shfl_xor(s, 8);
    q += __shfl_xor(q, 1); q += __shfl_xor(q, 2);
    q += __shfl_xor(q, 4); q += __shfl_xor(q, 8);
    if (jcol == 0) { redS[wid][rbase + r] = s; redQ[wid][rbase + r] = q; }
  }
  __syncthreads();
  #pragma unroll
  for (int r = 0; r < 4; ++r) {
    int row = rbase + r;
    float S = redS[0][row] + redS[1][row] + redS[2][row] + redS[3][row];
    float Q = redQ[0][row] + redQ[1][row] + redQ[2][row] + redQ[3][row];
    float mean = S * (1.0f / 128.0f);
    float var = Q * (1.0f / 128.0f) - mean * mean;
    float rs = rsqrtf(var + 1e-5f);
    #pragma unroll
    for (int jt = 0; jt < 2; ++jt) {
      float y = (acc[jt][r] - mean) * rs * gv[jt] + bev[jt];
      y = fmaxf(y, 0.f);
      st[row * 136 + wid * 32 + jt * 16 + jcol] = f2bf(y);
    }
  }
  __syncthreads();
  // cooperative readback: 256 threads x 16B = the whole 8KB tile in one shot
  int t = threadIdx.x;
  int row = t >> 4;
  int c = t & 15;
  uint4 v = *(const uint4*)&st[row * 136 + c * 8];
  *(uint4*)(outh + (size_t)(ntile * 16 + row) * DH + c * 8) = v;
}

// ---------------- final linear + x-copy: out[n] = [x[n], h@lin_w.T + lin_b] ---
// Column-quadrant: 1 block (4 waves) per tile; wave wid owns cols [wid*64,+64).
// Block LDS stage, barrier, full-1KB-row coalesced stores.
__global__ __launch_bounds__(256) void final_kernel(const u16* __restrict__ A,
                                                    const u16* __restrict__ W,
                                                    const float* __restrict__ bias,
                                                    const float* __restrict__ x,
                                                    float* __restrict__ out) {
  __shared__ float smw[16 * 268];     // 268-float stride: 16B-aligned, <=2-way alias
  int lane = threadIdx.x & 63;
  int wid = threadIdx.x >> 6;
  int ntile = blockIdx.x;
  int rA = lane & 15;
  int ksel = lane >> 4;
  int nodeA = ntile * 16 + rA;

  f32x4 acc[4];
  #pragma unroll
  for (int j = 0; j < 4; ++j) acc[j] = (f32x4){0.f,0.f,0.f,0.f};

  const u16* arow = A + (size_t)nodeA * DH + ksel * 8;
  #pragma unroll
  for (int ks = 0; ks < 4; ++ks) {
    bf16x8 af = *(const bf16x8*)(arow + ks * 32);
    #pragma unroll
    for (int jt2 = 0; jt2 < 4; ++jt2) {
      int jt = wid * 4 + jt2;
      const u16* wfrag = W + (size_t)(jt * 16 + rA) * DH + ksel * 8 + ks * 32;
      bf16x8 bf = *(const bf16x8*)wfrag;
      acc[jt2] = __builtin_amdgcn_mfma_f32_16x16x32_bf16(af, bf, acc[jt2], 0, 0, 0);
    }
  }

  int jcol = lane & 15;
  int rbase = (lane >> 4) * 4;
  int base = ntile * 16;

  #pragma unroll
  for (int jt2 = 0; jt2 < 4; ++jt2) {
    float bv = bias[(wid * 4 + jt2) * 16 + jcol];
    #pragma unroll
    for (int r = 0; r < 4; ++r)
      smw[(rbase + r) * 268 + wid * 64 + jt2 * 16 + jcol] = acc[jt2][r] + bv;
  }

  // x -> out[:,0:128] (independent of LDS; overlaps the stage)
  #pragma unroll
  for (int i = 0; i < 2; ++i) {
    int idx = i * 256 + threadIdx.x;
    int rr = idx >> 5;
    int cc = idx & 31;
    f32x4 v = *(const f32x4*)(x + (size_t)(base + rr) * DH + cc * 4);
    *(f32x4*)(out + (size_t)(base + rr) * 384 + cc * 4) = v;
  }

  __syncthreads();
  // linear part: each wave stores one full 1KB contiguous row per iteration
  #pragma unroll
  for (int i = 0; i < 4; ++i) {
    int row = i * 4 + wid;
    f32x4 v = *(const f32x4*)&smw[row * 268 + lane * 4];
    *(f32x4*)(out + (size_t)(base + row) * 384 + 128 + lane * 4) = v;
  }
}

extern "C" void kernel_launch(void* const* d_in, const int* in_sizes, int n_in,
                              void* d_out, int out_size, void* d_ws, size_t ws_size,
                              hipStream_t stream) {
  const float* x      = (const float*)d_in[0];
  const int*   ei     = (const int*)d_in[1];
  const float* pre_w  = (const float*)d_in[2];
  const float* pre_b  = (const float*)d_in[3];
  const float* pre_g  = (const float*)d_in[4];
  const float* pre_be = (const float*)d_in[5];
  const float* wl0    = (const float*)d_in[6];
  const float* wr0    = (const float*)d_in[7];
  const float* b0     = (const float*)d_in[8];
  const float* g0     = (const float*)d_in[9];
  const float* be0    = (const float*)d_in[10];
  const float* wl1    = (const float*)d_in[11];
  const float* wr1    = (const float*)d_in[12];
  const float* b1     = (const float*)d_in[13];
  const float* g1     = (const float*)d_in[14];
  const float* be1    = (const float*)d_in[15];
  const float* lin_w  = (const float*)d_in[16];
  const float* lin_b  = (const float*)d_in[17];
  float* out = (float*)d_out;

  char* ws = (char*)d_ws;
  size_t o = 0;
  auto alloc = [&](size_t bytes) { void* p = ws + o; o += (bytes + 255) & ~255ULL; return p; };
  u16* xb   = (u16*)alloc((size_t)NN * DH * 2);
  u16* hA   = (u16*)alloc((size_t)NN * DH * 2);
  u16* hB   = (u16*)alloc((size_t)NN * DH * 2);
  u16* aggb = (u16*)alloc((size_t)NN * DH * 2);
  u16* wb   = (u16*)alloc((size_t)114688 * 2);
  int* cnt     = (int*)alloc((size_t)NN * 4);
  int* off     = (int*)alloc((size_t)(NN + 1) * 4);
  int* fillpos = (int*)alloc((size_t)NN * 4);
  int* srcs    = (int*)alloc((size_t)NE * 4);
  int* partial = (int*)alloc((size_t)NBLK * 4);

  {
    long total4 = ((long)NN * DH + 114688 + NN) / 4;
    int blocks = (int)((total4 + 255) / 256);
    cast_all<<<blocks, 256, 0, stream>>>(x, pre_w, wl0, wr0, wl1, wr1, lin_w, xb, wb, cnt);
  }
  count_kernel<<<NE / 256, 256, 0, stream>>>(ei, cnt);
  scan_part<<<NBLK, 256, 0, stream>>>(cnt, partial);
  scan_top<<<1, 256, 0, stream>>>(partial);
  scan_final<<<NBLK, 256, 0, stream>>>(cnt, partial, off, fillpos);
  fill_kernel<<<NE / 256, 256, 0, stream>>>(ei, fillpos, srcs);

  // pre-MP layer
  gemm_ln_relu<<<NTILES, 256, 0, stream>>>(xb, wb + 0, nullptr, nullptr,
                                           pre_b, pre_g, pre_be, hA);
  // SAGE layer 0
  agg_kernel<<<NN / 4, 256, 0, stream>>>(hA, off, srcs, aggb);
  gemm_ln_relu<<<NTILES, 256, 0, stream>>>(aggb, wb + 16384, hA, wb + 32768,
                                           b0, g0, be0, hB);
  // SAGE layer 1
  agg_kernel<<<NN / 4, 256, 0, stream>>>(hB, off, srcs, aggb);
  gemm_ln_relu<<<NTILES, 256, 0, stream>>>(aggb, wb + 49152, hB, wb + 65536,
                                           b1, g1, be1, hA);
  // output (linear + x concat fused)
  final_kernel<<<NTILES, 256, 0, stream>>>(hA, wb + 81920, lin_b, x, out);
}